// Round 1
// baseline (111.159 us; speedup 1.0000x reference)
//
#include <hip/hip_runtime.h>

// out[e] = relu(relu(features[src[e]] @ W1 + b1) @ W2 + b2)
// Factored: per-node MLP (N=50k) into workspace, then per-edge gather (E=800k).

// One wave (64 lanes) per row. Lane d computes element d of h and y.
// Block = 256 threads = 4 rows. x and h staged in LDS; reads are wave-uniform
// address -> LDS broadcast, conflict-free. W reads are 256B coalesced, L1-hot.
__global__ __launch_bounds__(256) void mlp_rows_kernel(
    const float* __restrict__ features,
    const int* __restrict__ idx,   // nullptr: row -> features[row]; else features[idx[row]]
    const float* __restrict__ W1, const float* __restrict__ b1,
    const float* __restrict__ W2, const float* __restrict__ b2,
    float* __restrict__ out, int nrows)
{
    __shared__ float xs[4][64];
    __shared__ float hs[4][64];

    const int lane = threadIdx.x & 63;
    const int sub  = threadIdx.x >> 6;           // which of the 4 rows
    const int row  = blockIdx.x * 4 + sub;

    if (row < nrows) {
        const int n = idx ? idx[row] : row;
        xs[sub][lane] = features[(long long)n * 64 + lane];
    }
    __syncthreads();

    if (row < nrows) {
        float h = b1[lane];
        #pragma unroll
        for (int k = 0; k < 64; ++k)
            h = fmaf(xs[sub][k], W1[k * 64 + lane], h);
        hs[sub][lane] = fmaxf(h, 0.0f);
    }
    __syncthreads();

    if (row < nrows) {
        float y = b2[lane];
        #pragma unroll
        for (int k = 0; k < 64; ++k)
            y = fmaf(hs[sub][k], W2[k * 64 + lane], y);
        out[(long long)row * 64 + lane] = fmaxf(y, 0.0f);
    }
}

// out[e][:] = Y[src[e]][:], vectorized as 16 x float4 per edge.
__global__ __launch_bounds__(256) void gather_kernel(
    const float4* __restrict__ Y,   // [N][16] float4
    const int* __restrict__ src,    // [E]
    float4* __restrict__ out,       // [E][16] float4
    long long total)                // E*16
{
    const long long stride = (long long)gridDim.x * blockDim.x;
    for (long long g = (long long)blockIdx.x * blockDim.x + threadIdx.x;
         g < total; g += stride) {
        const long long e = g >> 4;
        const int j = (int)(g & 15);
        const int n = src[e];
        out[g] = Y[(long long)n * 16 + j];
    }
}

extern "C" void kernel_launch(void* const* d_in, const int* in_sizes, int n_in,
                              void* d_out, int out_size, void* d_ws, size_t ws_size,
                              hipStream_t stream) {
    const float* features = (const float*)d_in[0];
    const int*   src      = (const int*)  d_in[1];
    const float* W1       = (const float*)d_in[2];
    const float* b1       = (const float*)d_in[3];
    const float* W2       = (const float*)d_in[4];
    const float* b2       = (const float*)d_in[5];
    float* out = (float*)d_out;

    const int N = in_sizes[0] / 64;
    const int E = in_sizes[1];

    const size_t need = (size_t)N * 64 * sizeof(float);
    if (ws_size >= need) {
        // Phase 1: per-node MLP into workspace
        float* Y = (float*)d_ws;
        mlp_rows_kernel<<<(N + 3) / 4, 256, 0, stream>>>(
            features, nullptr, W1, b1, W2, b2, Y, N);
        // Phase 2: gather per edge
        const long long total = (long long)E * 16;
        int blocks = (int)((total + 255) / 256);
        if (blocks > 16384) blocks = 16384;
        gather_kernel<<<blocks, 256, 0, stream>>>(
            (const float4*)Y, src, (float4*)out, total);
    } else {
        // Fallback: per-edge MLP directly into out (correct, slower)
        mlp_rows_kernel<<<(E + 3) / 4, 256, 0, stream>>>(
            features, src, W1, b1, W2, b2, out, E);
    }
}

// Round 4
// 88.725 us; speedup vs baseline: 1.2528x; 1.2528x over previous
//
#include <hip/hip_runtime.h>

typedef float f32x4 __attribute__((ext_vector_type(4)));

// out[e] = relu(relu(features[src[e]] @ W1 + b1) @ W2 + b2)
// Factored: per-node MLP (N=50k) into workspace, then per-edge gather (E=800k).

__device__ __forceinline__ float bcast(float v, int l) {
    return __int_as_float(__builtin_amdgcn_readlane(__float_as_int(v), l));
}

// One wave processes rows in a grid-stride loop. Lane j owns output column j:
// W1[:,j] and W2[:,j] live in 128 VGPRs (loaded once, reused for ~16 rows).
// x[k]/h[k] broadcasts via v_readlane (VALU) — no LDS, no per-FMA global loads.
__global__ __launch_bounds__(256, 3) void mlp_nodes_kernel(
    const float* __restrict__ features,
    const int* __restrict__ idx,   // nullptr: row -> features[row]; else features[idx[row]]
    const float* __restrict__ W1, const float* __restrict__ b1,
    const float* __restrict__ W2, const float* __restrict__ b2,
    float* __restrict__ out, int nrows)
{
    const int lane   = threadIdx.x & 63;
    const int wid    = (blockIdx.x * blockDim.x + threadIdx.x) >> 6;
    const int nwaves = (gridDim.x * blockDim.x) >> 6;

    float w1c[64], w2c[64];
    #pragma unroll
    for (int k = 0; k < 64; ++k) w1c[k] = W1[k * 64 + lane];
    #pragma unroll
    for (int k = 0; k < 64; ++k) w2c[k] = W2[k * 64 + lane];
    const float hb = b1[lane];
    const float yb = b2[lane];

    for (int row = wid; row < nrows; row += nwaves) {
        const int n = idx ? idx[row] : row;
        const float x = features[(long long)n * 64 + lane];

        // layer 1: h[lane] = relu(b1[lane] + sum_k x[k] * W1[k][lane])
        float a0 = hb, a1 = 0.f, a2 = 0.f, a3 = 0.f;
        #pragma unroll
        for (int k = 0; k < 64; k += 4) {
            a0 = fmaf(bcast(x, k + 0), w1c[k + 0], a0);
            a1 = fmaf(bcast(x, k + 1), w1c[k + 1], a1);
            a2 = fmaf(bcast(x, k + 2), w1c[k + 2], a2);
            a3 = fmaf(bcast(x, k + 3), w1c[k + 3], a3);
        }
        const float h = fmaxf((a0 + a1) + (a2 + a3), 0.0f);

        // layer 2: y[lane] = relu(b2[lane] + sum_k h[k] * W2[k][lane])
        float c0 = yb, c1 = 0.f, c2 = 0.f, c3 = 0.f;
        #pragma unroll
        for (int k = 0; k < 64; k += 4) {
            c0 = fmaf(bcast(h, k + 0), w2c[k + 0], c0);
            c1 = fmaf(bcast(h, k + 1), w2c[k + 1], c1);
            c2 = fmaf(bcast(h, k + 2), w2c[k + 2], c2);
            c3 = fmaf(bcast(h, k + 3), w2c[k + 3], c3);
        }
        out[(long long)row * 64 + lane] = fmaxf((c0 + c1) + (c2 + c3), 0.0f);
    }
}

// out[e][:] = Y[src[e]][:], 16 x float4 per edge; nontemporal streaming stores.
__global__ __launch_bounds__(256) void gather_kernel(
    const f32x4* __restrict__ Y,    // [N][16] float4
    const int* __restrict__ src,    // [E]
    f32x4* __restrict__ out,        // [E][16] float4
    long long total)                // E*16
{
    const long long stride = (long long)gridDim.x * blockDim.x;
    for (long long g = (long long)blockIdx.x * blockDim.x + threadIdx.x;
         g < total; g += stride) {
        const long long e = g >> 4;
        const int j = (int)(g & 15);
        const int n = src[e];
        f32x4 v = Y[(long long)n * 16 + j];
        __builtin_nontemporal_store(v, &out[g]);
    }
}

extern "C" void kernel_launch(void* const* d_in, const int* in_sizes, int n_in,
                              void* d_out, int out_size, void* d_ws, size_t ws_size,
                              hipStream_t stream) {
    const float* features = (const float*)d_in[0];
    const int*   src      = (const int*)  d_in[1];
    const float* W1       = (const float*)d_in[2];
    const float* b1       = (const float*)d_in[3];
    const float* W2       = (const float*)d_in[4];
    const float* b2       = (const float*)d_in[5];
    float* out = (float*)d_out;

    const int N = in_sizes[0] / 64;
    const int E = in_sizes[1];

    const size_t need = (size_t)N * 64 * sizeof(float);
    if (ws_size >= need) {
        // Phase 1: per-node MLP into workspace (768 blocks = 3072 waves,
        // exactly 3 waves/SIMD resident at 256 CUs; ~16 rows/wave amortizes
        // the 128-VGPR weight load).
        float* Y = (float*)d_ws;
        mlp_nodes_kernel<<<768, 256, 0, stream>>>(
            features, nullptr, W1, b1, W2, b2, Y, N);
        // Phase 2: gather per edge
        const long long total = (long long)E * 16;
        gather_kernel<<<4096, 256, 0, stream>>>(
            (const f32x4*)Y, src, (f32x4*)out, total);
    } else {
        // Fallback: per-edge MLP directly into out (correct, slower)
        mlp_nodes_kernel<<<3072, 256, 0, stream>>>(
            features, src, W1, b1, W2, b2, out, E);
    }
}